// Round 5
// baseline (2571.590 us; speedup 1.0000x reference)
//
#include <hip/hip_runtime.h>
#include <math.h>

#define LDIM 2048
#define DDIM 128
#define BDIM 16
#define FDIM 100
#define TCONV 16
#define NB2 32        // 32 partial slices of 64 rows/cols
#define KSPLIT 384    // storage: 3x128 bf16 slices [h|m|l]

typedef short short8 __attribute__((ext_vector_type(8)));
typedef float floatx4 __attribute__((ext_vector_type(4)));

__device__ __forceinline__ unsigned short f2bf(float x) {   // RNE fp32 -> bf16 bits
  unsigned int u = __float_as_uint(x);
  return (unsigned short)((u + 0x7fffu + ((u >> 16) & 1u)) >> 16);
}
__device__ __forceinline__ float bf2f(unsigned short b) {
  return __uint_as_float(((unsigned int)b) << 16);
}

__device__ __forceinline__ void ins3r(float w, int idx, float& v0, float& v1, float& v2,
                                      int& i0, int& i1, int& i2) {
  if (w > v2) {
    if (w > v0) { v2=v1; i2=i1; v1=v0; i1=i0; v0=w; i0=idx; }
    else if (w > v1) { v2=v1; i2=i1; v1=w; i1=idx; }
    else { v2=w; i2=idx; }
  }
}

// fp32 -> (hi, mid, lo) bf16 triple, K-concatenated: row layout [384]: h[128] m[128] l[128]
// Splits are exact (Sterbenz): x = h + m + l + O(2^-27 |x|).
__global__ __launch_bounds__(256) void split_bf16(const float* __restrict__ ctx,
    const float* __restrict__ mn, unsigned short* __restrict__ A3,
    unsigned short* __restrict__ B3) {
  const float* src = blockIdx.y ? mn : ctx;
  unsigned short* dst = blockIdx.y ? B3 : A3;
  int gid = blockIdx.x * 256 + threadIdx.x;       // over nb*2048*32 quads
  int row = gid >> 5, g = gid & 31;
  float4 x = ((const float4*)src)[(size_t)row*32 + g];
  float xs[4] = {x.x, x.y, x.z, x.w};
  unsigned short hs[4], ms[4], ls[4];
  #pragma unroll
  for (int i = 0; i < 4; i++) {
    hs[i] = f2bf(xs[i]);
    float r1 = xs[i] - bf2f(hs[i]);
    ms[i] = f2bf(r1);
    float r2 = r1 - bf2f(ms[i]);
    ls[i] = f2bf(r2);
  }
  ushort4 h = {hs[0],hs[1],hs[2],hs[3]};
  ushort4 m = {ms[0],ms[1],ms[2],ms[3]};
  ushort4 l = {ls[0],ls[1],ls[2],ls[3]};
  size_t base = (size_t)row * KSPLIT + g*4;
  *(ushort4*)&dst[base]       = h;
  *(ushort4*)&dst[base + 128] = m;
  *(ushort4*)&dst[base + 256] = l;
}

// MFMA GEMM at fp32-equivalent precision via 6 slice-pair products:
// (h,h) (h,m) (m,h) (h,l) (l,h) (m,m)  -> effective K=768 bf16.
// Fused per-64-slice row/col {top3,sum,sq} partials.
// rowPart[(b*NB2 + mslice)*LDIM + c][8] = {v0,v1,v2,i0,i1,i2,sum,sq}; colPart analogous.
__global__ __launch_bounds__(256) void gemm_mfma(const unsigned short* __restrict__ A3,
    const unsigned short* __restrict__ B3, float* __restrict__ rowPart,
    float* __restrict__ colPart) {
  __shared__ __attribute__((aligned(16))) unsigned short As[128][40];
  __shared__ __attribute__((aligned(16))) unsigned short Bs[128][40];
  const int b = blockIdx.z, cb = blockIdx.y, mb = blockIdx.x;
  const int c0 = cb*128, m0 = mb*128;
  const int tid = threadIdx.x;
  const int lane = tid & 63, wave = tid >> 6;
  const int wx = wave & 1, wy = wave >> 1;        // wave -> 64x64 quadrant
  const int l15 = lane & 15, quad = lane >> 4;

  floatx4 acc[4][4];
  #pragma unroll
  for (int i = 0; i < 4; i++)
    #pragma unroll
    for (int j = 0; j < 4; j++) acc[i][j] = (floatx4){0.f, 0.f, 0.f, 0.f};

  const unsigned short* Ab = A3 + (size_t)b*LDIM*KSPLIT;
  const unsigned short* Bb = B3 + (size_t)b*LDIM*KSPLIT;

  // slice pairs: all products >= 2^-18 relative (ml/lm/ll ~ 2^-27 dropped)
  #pragma unroll
  for (int p = 0; p < 6; p++) {
    constexpr int PA[6] = {0, 0, 1, 0, 2, 1};
    constexpr int PB[6] = {0, 1, 0, 2, 0, 1};
    const int oa = PA[p]*128, ob = PB[p]*128;
    #pragma unroll
    for (int t4 = 0; t4 < 4; t4++) {              // 4 sub-chunks of K=32
      __syncthreads();
      #pragma unroll
      for (int u = 0; u < 2; u++) {
        int e = tid + u*256;
        int r = e >> 2, q = e & 3;
        *(short8*)&As[r][q*8] = *(const short8*)&Ab[(size_t)(c0 + r)*KSPLIT + oa + t4*32 + q*8];
        *(short8*)&Bs[r][q*8] = *(const short8*)&Bb[(size_t)(m0 + r)*KSPLIT + ob + t4*32 + q*8];
      }
      __syncthreads();
      short8 af[4], bfr[4];
      #pragma unroll
      for (int i = 0; i < 4; i++) af[i]  = *(const short8*)&As[wy*64 + i*16 + l15][quad*8];
      #pragma unroll
      for (int j = 0; j < 4; j++) bfr[j] = *(const short8*)&Bs[wx*64 + j*16 + l15][quad*8];
      #pragma unroll
      for (int i = 0; i < 4; i++)
        #pragma unroll
        for (int j = 0; j < 4; j++)
          acc[i][j] = __builtin_amdgcn_mfma_f32_16x16x32_bf16(af[i], bfr[j], acc[i][j], 0, 0, 0);
    }
  }

  // ---- row partials: reduce each row over this wave's 64 cols ----
  #pragma unroll
  for (int i = 0; i < 4; i++) {
    #pragma unroll
    for (int r = 0; r < 4; r++) {
      float v0=-3e38f, v1=-3e38f, v2=-3e38f; int i0=-1, i1=-1, i2=-1;
      float s = 0.f, q = 0.f;
      #pragma unroll
      for (int j = 0; j < 4; j++) {
        float w = acc[i][j][r];
        s += w; q += w*w;
        ins3r(w, m0 + wx*64 + j*16 + l15, v0,v1,v2,i0,i1,i2);
      }
      #pragma unroll
      for (int msk = 1; msk < 16; msk <<= 1) {    // reduce over l15 (same quad/row)
        float ov0=__shfl_xor(v0,msk,16), ov1=__shfl_xor(v1,msk,16), ov2=__shfl_xor(v2,msk,16);
        int   oi0=__shfl_xor(i0,msk,16), oi1=__shfl_xor(i1,msk,16), oi2=__shfl_xor(i2,msk,16);
        float os =__shfl_xor(s,msk,16),  oq =__shfl_xor(q,msk,16);
        s += os; q += oq;
        ins3r(ov0,oi0,v0,v1,v2,i0,i1,i2);
        ins3r(ov1,oi1,v0,v1,v2,i0,i1,i2);
        ins3r(ov2,oi2,v0,v1,v2,i0,i1,i2);
      }
      if (l15 == 0) {
        int row = c0 + wy*64 + i*16 + quad*4 + r;
        float* p = rowPart + ((size_t)(b*NB2 + mb*2 + wx)*LDIM + row) * 8;
        float4 lo = {v0, v1, v2, __int_as_float(i0)};
        float4 hi = {__int_as_float(i1), __int_as_float(i2), s, q};
        *(float4*)p = lo; *(float4*)(p+4) = hi;
      }
    }
  }

  // ---- col partials: reduce each col over this wave's 64 rows ----
  #pragma unroll
  for (int j = 0; j < 4; j++) {
    float v0=-3e38f, v1=-3e38f, v2=-3e38f; int i0=-1, i1=-1, i2=-1;
    float s = 0.f, q = 0.f;
    #pragma unroll
    for (int i = 0; i < 4; i++)
      #pragma unroll
      for (int r = 0; r < 4; r++) {
        float w = acc[i][j][r];
        s += w; q += w*w;
        ins3r(w, c0 + wy*64 + i*16 + quad*4 + r, v0,v1,v2,i0,i1,i2);
      }
    #pragma unroll
    for (int msk = 16; msk < 64; msk <<= 1) {     // reduce over quad (same col)
      float ov0=__shfl_xor(v0,msk), ov1=__shfl_xor(v1,msk), ov2=__shfl_xor(v2,msk);
      int   oi0=__shfl_xor(i0,msk), oi1=__shfl_xor(i1,msk), oi2=__shfl_xor(i2,msk);
      float os =__shfl_xor(s,msk),  oq =__shfl_xor(q,msk);
      s += os; q += oq;
      ins3r(ov0,oi0,v0,v1,v2,i0,i1,i2);
      ins3r(ov1,oi1,v0,v1,v2,i0,i1,i2);
      ins3r(ov2,oi2,v0,v1,v2,i0,i1,i2);
    }
    if (quad == 0) {
      int col = m0 + wx*64 + j*16 + l15;
      float* p = colPart + ((size_t)(b*NB2 + cb*2 + wy)*LDIM + col) * 8;
      float4 lo = {v0, v1, v2, __int_as_float(i0)};
      float4 hi = {__int_as_float(i1), __int_as_float(i2), s, q};
      *(float4*)p = lo; *(float4*)(p+4) = hi;
    }
  }
}

// Merge NB2 slice-partials per line -> normalized top-3 weights, indices, std.
__global__ __launch_bounds__(256) void reduce_stats(const float* __restrict__ part,
    float* __restrict__ w3, int* __restrict__ i3, float* __restrict__ sd) {
  int gid = blockIdx.x * 256 + threadIdx.x;       // over nb*LDIM lines
  int b = gid >> 11, r = gid & 2047;
  float v0=-3e38f, v1=-3e38f, v2=-3e38f; int i0=-1, i1=-1, i2=-1;
  float s = 0.f, q = 0.f;
  for (int blk = 0; blk < NB2; blk++) {
    const float* p = part + ((size_t)(b*NB2 + blk)*LDIM + r) * 8;
    float4 lo = *(const float4*)p, hi = *(const float4*)(p+4);
    ins3r(lo.x, __float_as_int(lo.w), v0,v1,v2,i0,i1,i2);
    ins3r(lo.y, __float_as_int(hi.x), v0,v1,v2,i0,i1,i2);
    ins3r(lo.z, __float_as_int(hi.y), v0,v1,v2,i0,i1,i2);
    s += hi.z; q += hi.w;
  }
  float inv = 1.f / (v0 + v1 + v2);
  w3[(size_t)gid*3+0] = v0*inv; w3[(size_t)gid*3+1] = v1*inv; w3[(size_t)gid*3+2] = v2*inv;
  i3[(size_t)gid*3+0] = i0; i3[(size_t)gid*3+1] = i1; i3[(size_t)gid*3+2] = i2;
  float mean = s * (1.f/LDIM);
  float var  = q * (1.f/LDIM) - mean*mean;
  sd[gid] = sqrtf(fmaxf(var, 0.f));
}

// att_merge_c[m][d] += wk_c[c][m] * ctx[c][d]  -- 3 targets per row c (scatter).
__global__ __launch_bounds__(128) void scatter_att(const float* __restrict__ ctx,
    const float* __restrict__ rw, const int* __restrict__ ri,
    float* __restrict__ attC) {
  const int b = blockIdx.y, c = blockIdx.x, d = threadIdx.x;
  const size_t base = (size_t)b*LDIM + c;
  const float x = ctx[base*DDIM + d];
  #pragma unroll
  for (int t = 0; t < 3; t++) {
    float w = rw[base*3 + t];
    int m = ri[base*3 + t];
    atomicAdd(&attC[((size_t)b*LDIM + m)*DDIM + d], w*x);
  }
}

// outputs_c = |ctx - gather(col top-3 of main)| * row_std ; outputs_m = |main - attC| * col_std
__global__ __launch_bounds__(128) void make_outputs(const float* __restrict__ ctx,
    const float* __restrict__ mn, const float* __restrict__ attC,
    const float* __restrict__ rs, const float* __restrict__ cw,
    const int* __restrict__ ci, const float* __restrict__ cs,
    float* __restrict__ outC, float* __restrict__ outM) {
  const int b = blockIdx.y, i = blockIdx.x, d = threadIdx.x;
  const size_t base = (size_t)b*LDIM + i;
  float am = 0.f;
  #pragma unroll
  for (int t = 0; t < 3; t++)
    am += cw[base*3+t] * mn[((size_t)b*LDIM + ci[base*3+t])*DDIM + d];
  outC[base*DDIM + d] = fabsf(ctx[base*DDIM + d] - am) * rs[base];
  outM[base*DDIM + d] = fabsf(mn[base*DDIM + d] - attC[base*DDIM + d]) * cs[base];
}

// conv1d(KS=3, valid) + bias + relu + maxpool. z=0: outC->pool_c, z=1: outM->pool_m.
__global__ __launch_bounds__(128) void conv_pool(const float* __restrict__ XC,
    const float* __restrict__ XM, const float* __restrict__ wv,
    const float* __restrict__ bias, float* __restrict__ out) {
  const int b = blockIdx.y, z = blockIdx.z;
  const int t0 = blockIdx.x * TCONV;
  const float* X = (z == 0 ? XC : XM) + (size_t)b*LDIM*DDIM;
  __shared__ float Xs[TCONV+2][DDIM];
  const int tid = threadIdx.x;
  for (int e = tid; e < (TCONV+2)*DDIM; e += 128) {
    int tt = e >> 7, d = e & 127;
    int t = t0 + tt;
    Xs[tt][d] = (t < LDIM) ? X[(size_t)t*DDIM + d] : 0.f;
  }
  __syncthreads();
  const int f = tid;
  if (f < FDIM) {
    float y[TCONV];
    #pragma unroll
    for (int t = 0; t < TCONV; t++) y[t] = 0.f;
    for (int dq = 0; dq < DDIM/4; dq++) {
      float4 xq[TCONV+2];
      #pragma unroll
      for (int i = 0; i < TCONV+2; i++) xq[i] = *(const float4*)&Xs[i][dq*4];
      #pragma unroll
      for (int ks = 0; ks < 3; ks++) {
        float w0 = wv[(ks*DDIM + dq*4+0)*FDIM + f];
        float w1 = wv[(ks*DDIM + dq*4+1)*FDIM + f];
        float w2 = wv[(ks*DDIM + dq*4+2)*FDIM + f];
        float w3 = wv[(ks*DDIM + dq*4+3)*FDIM + f];
        #pragma unroll
        for (int t = 0; t < TCONV; t++)
          y[t] += xq[t+ks].x*w0 + xq[t+ks].y*w1 + xq[t+ks].z*w2 + xq[t+ks].w*w3;
      }
    }
    float bv = bias[f];
    float mx = 0.f;
    #pragma unroll
    for (int t = 0; t < TCONV; t++) {
      if (t0 + t < LDIM - 2) mx = fmaxf(mx, fmaxf(y[t] + bv, 0.f));
    }
    atomicMax((unsigned int*)&out[(size_t)b*(2*FDIM) + z*FDIM + f], __float_as_uint(mx));
  }
}

extern "C" void kernel_launch(void* const* d_in, const int* in_sizes, int n_in,
                              void* d_out, int out_size, void* d_ws, size_t ws_size,
                              hipStream_t stream) {
  const float* ctx   = (const float*)d_in[0];
  const float* mn    = (const float*)d_in[1];
  const float* wconv = (const float*)d_in[2];
  const float* bias  = (const float*)d_in[3];
  float* out = (float*)d_out;

  hipMemsetAsync(d_out, 0, sizeof(float)*(size_t)out_size, stream);

  const size_t PB_SPLIT = (size_t)LDIM*KSPLIT/2;              // in float units
  const size_t PB_PART  = (size_t)NB2*LDIM*8;
  const size_t perBatchFloats = 2*PB_SPLIT + 2*PB_PART + 14*(size_t)LDIM + 3*(size_t)LDIM*DDIM;
  const size_t perBatchBytes = perBatchFloats * sizeof(float);
  int nbMax = (int)(ws_size / perBatchBytes);
  if (nbMax < 1) nbMax = 1;
  if (nbMax > BDIM) nbMax = BDIM;

  for (int b0 = 0; b0 < BDIM; b0 += nbMax) {
    const int nb = (BDIM - b0 < nbMax) ? (BDIM - b0) : nbMax;
    unsigned short* A3u = (unsigned short*)d_ws;
    unsigned short* B3u = A3u + (size_t)nb*LDIM*KSPLIT;
    float* rowPart = (float*)d_ws + 2*(size_t)nb*PB_SPLIT;
    float* colPart = rowPart + (size_t)nb*PB_PART;
    float* rowW = colPart + (size_t)nb*PB_PART;
    int*   rowI = (int*)(rowW + (size_t)nb*LDIM*3);
    float* rowS = (float*)(rowI + (size_t)nb*LDIM*3);
    float* colW = rowS + (size_t)nb*LDIM;
    int*   colI = (int*)(colW + (size_t)nb*LDIM*3);
    float* colS = (float*)(colI + (size_t)nb*LDIM*3);
    float* attC = colS + (size_t)nb*LDIM;
    float* outC = attC + (size_t)nb*LDIM*DDIM;
    float* outM = outC + (size_t)nb*LDIM*DDIM;
    const float* ctxb = ctx + (size_t)b0*LDIM*DDIM;
    const float* mnb  = mn  + (size_t)b0*LDIM*DDIM;

    split_bf16<<<dim3(nb*256, 2), 256, 0, stream>>>(ctxb, mnb, A3u, B3u);
    gemm_mfma<<<dim3(NB2/2, NB2/2, nb), 256, 0, stream>>>(A3u, B3u, rowPart, colPart);
    reduce_stats<<<dim3(nb*8), 256, 0, stream>>>(rowPart, rowW, rowI, rowS);
    reduce_stats<<<dim3(nb*8), 256, 0, stream>>>(colPart, colW, colI, colS);
    hipMemsetAsync(attC, 0, (size_t)nb*LDIM*DDIM*sizeof(float), stream);
    scatter_att<<<dim3(LDIM, nb), 128, 0, stream>>>(ctxb, rowW, rowI, attC);
    make_outputs<<<dim3(LDIM, nb), 128, 0, stream>>>(ctxb, mnb, attC, rowS, colW, colI, colS, outC, outM);
    conv_pool<<<dim3((LDIM - 2 + TCONV - 1)/TCONV, nb, 2), 128, 0, stream>>>(
        outC, outM, wconv, bias, out + (size_t)b0*2*FDIM);
  }
}

// Round 6
// 2498.248 us; speedup vs baseline: 1.0294x; 1.0294x over previous
//
#include <hip/hip_runtime.h>
#include <math.h>

#define LDIM 2048
#define DDIM 128
#define BDIM 16
#define FDIM 100
#define TCONV 16
#define NB2 32        // 32 partial slices of 64 rows/cols
#define KSPLIT 384    // storage: 3x128 bf16 slices [h|m|l]

typedef short short8 __attribute__((ext_vector_type(8)));
typedef float floatx4 __attribute__((ext_vector_type(4)));

__device__ __forceinline__ unsigned short f2bf(float x) {   // RNE fp32 -> bf16 bits
  unsigned int u = __float_as_uint(x);
  return (unsigned short)((u + 0x7fffu + ((u >> 16) & 1u)) >> 16);
}
__device__ __forceinline__ float bf2f(unsigned short b) {
  return __uint_as_float(((unsigned int)b) << 16);
}

__device__ __forceinline__ void ins3r(float w, int idx, float& v0, float& v1, float& v2,
                                      int& i0, int& i1, int& i2) {
  if (w > v2) {
    if (w > v0) { v2=v1; i2=i1; v1=v0; i1=i0; v0=w; i0=idx; }
    else if (w > v1) { v2=v1; i2=i1; v1=w; i1=idx; }
    else { v2=w; i2=idx; }
  }
}

// fp32 -> (hi, mid, lo) bf16 triple, K-concatenated: row layout [384]: h[128] m[128] l[128]
__global__ __launch_bounds__(256) void split_bf16(const float* __restrict__ ctx,
    const float* __restrict__ mn, unsigned short* __restrict__ A3,
    unsigned short* __restrict__ B3) {
  const float* src = blockIdx.y ? mn : ctx;
  unsigned short* dst = blockIdx.y ? B3 : A3;
  int gid = blockIdx.x * 256 + threadIdx.x;       // over nb*2048*32 quads
  int row = gid >> 5, g = gid & 31;
  float4 x = ((const float4*)src)[(size_t)row*32 + g];
  float xs[4] = {x.x, x.y, x.z, x.w};
  unsigned short hs[4], ms[4], ls[4];
  #pragma unroll
  for (int i = 0; i < 4; i++) {
    hs[i] = f2bf(xs[i]);
    float r1 = xs[i] - bf2f(hs[i]);
    ms[i] = f2bf(r1);
    float r2 = r1 - bf2f(ms[i]);
    ls[i] = f2bf(r2);
  }
  ushort4 h = {hs[0],hs[1],hs[2],hs[3]};
  ushort4 m = {ms[0],ms[1],ms[2],ms[3]};
  ushort4 l = {ls[0],ls[1],ls[2],ls[3]};
  size_t base = (size_t)row * KSPLIT + g*4;
  *(ushort4*)&dst[base]       = h;
  *(ushort4*)&dst[base + 128] = m;
  *(ushort4*)&dst[base + 256] = l;
}

// MFMA GEMM at fp32-equivalent precision via 6 slice-pair products {(sa,sb): sa+sb<=2}.
// Restructured K-loop: stage ALL 6 slices for one K=32 chunk (60 KB LDS), then run all
// 6 pair-products -> 96 MFMAs per barrier (was 16), 8 barriers (was 48).
// Fused per-64-slice row/col {top3,sum,sq} partials.
__global__ __launch_bounds__(256) void gemm_mfma(const unsigned short* __restrict__ A3,
    const unsigned short* __restrict__ B3, float* __restrict__ rowPart,
    float* __restrict__ colPart) {
  __shared__ __attribute__((aligned(16))) unsigned short smem_u[6*128*40];  // 61440 B
  unsigned short (*As)[128][40] = (unsigned short (*)[128][40])smem_u;
  unsigned short (*Bs)[128][40] = (unsigned short (*)[128][40])(smem_u + 3*128*40);
  const int b = blockIdx.z, cb = blockIdx.y, mb = blockIdx.x;
  const int c0 = cb*128, m0 = mb*128;
  const int tid = threadIdx.x;
  const int lane = tid & 63, wave = tid >> 6;
  const int wx = wave & 1, wy = wave >> 1;        // wave -> 64x64 quadrant
  const int l15 = lane & 15, quad = lane >> 4;

  floatx4 acc[4][4];
  #pragma unroll
  for (int i = 0; i < 4; i++)
    #pragma unroll
    for (int j = 0; j < 4; j++) acc[i][j] = (floatx4){0.f, 0.f, 0.f, 0.f};

  const unsigned short* Ab = A3 + (size_t)b*LDIM*KSPLIT;
  const unsigned short* Bb = B3 + (size_t)b*LDIM*KSPLIT;

  #pragma unroll
  for (int t = 0; t < 4; t++) {                   // K chunks of 32 (per slice)
    __syncthreads();
    #pragma unroll
    for (int u = 0; u < 2; u++) {
      int e = tid + u*256;
      int r = e >> 2, q = e & 3;                  // write banks 2-way max (free)
      #pragma unroll
      for (int s = 0; s < 3; s++) {
        *(short8*)&As[s][r][q*8] = *(const short8*)&Ab[(size_t)(c0 + r)*KSPLIT + s*128 + t*32 + q*8];
        *(short8*)&Bs[s][r][q*8] = *(const short8*)&Bb[(size_t)(m0 + r)*KSPLIT + s*128 + t*32 + q*8];
      }
    }
    __syncthreads();
    #pragma unroll
    for (int sa = 0; sa < 3; sa++) {              // A-frag register reuse across sb
      short8 af[4];
      #pragma unroll
      for (int i = 0; i < 4; i++) af[i] = *(const short8*)&As[sa][wy*64 + i*16 + l15][quad*8];
      #pragma unroll
      for (int sb = 0; sb < 3 - sa; sb++) {       // pairs with sa+sb <= 2
        short8 bfr[4];
        #pragma unroll
        for (int j = 0; j < 4; j++) bfr[j] = *(const short8*)&Bs[sb][wx*64 + j*16 + l15][quad*8];
        #pragma unroll
        for (int i = 0; i < 4; i++)
          #pragma unroll
          for (int j = 0; j < 4; j++)
            acc[i][j] = __builtin_amdgcn_mfma_f32_16x16x32_bf16(af[i], bfr[j], acc[i][j], 0, 0, 0);
      }
    }
  }

  // ---- row partials: reduce each row over this wave's 64 cols ----
  #pragma unroll
  for (int i = 0; i < 4; i++) {
    #pragma unroll
    for (int r = 0; r < 4; r++) {
      float v0=-3e38f, v1=-3e38f, v2=-3e38f; int i0=-1, i1=-1, i2=-1;
      float s = 0.f, q = 0.f;
      #pragma unroll
      for (int j = 0; j < 4; j++) {
        float w = acc[i][j][r];
        s += w; q += w*w;
        ins3r(w, m0 + wx*64 + j*16 + l15, v0,v1,v2,i0,i1,i2);
      }
      #pragma unroll
      for (int msk = 1; msk < 16; msk <<= 1) {    // reduce over l15 (same quad/row)
        float ov0=__shfl_xor(v0,msk,16), ov1=__shfl_xor(v1,msk,16), ov2=__shfl_xor(v2,msk,16);
        int   oi0=__shfl_xor(i0,msk,16), oi1=__shfl_xor(i1,msk,16), oi2=__shfl_xor(i2,msk,16);
        float os =__shfl_xor(s,msk,16),  oq =__shfl_xor(q,msk,16);
        s += os; q += oq;
        ins3r(ov0,oi0,v0,v1,v2,i0,i1,i2);
        ins3r(ov1,oi1,v0,v1,v2,i0,i1,i2);
        ins3r(ov2,oi2,v0,v1,v2,i0,i1,i2);
      }
      if (l15 == 0) {
        int row = c0 + wy*64 + i*16 + quad*4 + r;
        float* p = rowPart + ((size_t)(b*NB2 + mb*2 + wx)*LDIM + row) * 8;
        float4 lo = {v0, v1, v2, __int_as_float(i0)};
        float4 hi = {__int_as_float(i1), __int_as_float(i2), s, q};
        *(float4*)p = lo; *(float4*)(p+4) = hi;
      }
    }
  }

  // ---- col partials: reduce each col over this wave's 64 rows ----
  __syncthreads();                                // done with As/Bs; reuse as cbuf
  float* cbuf = (float*)smem_u;
  #pragma unroll
  for (int j = 0; j < 4; j++) {
    float v0=-3e38f, v1=-3e38f, v2=-3e38f; int i0=-1, i1=-1, i2=-1;
    float s = 0.f, q = 0.f;
    #pragma unroll
    for (int i = 0; i < 4; i++)
      #pragma unroll
      for (int r = 0; r < 4; r++) {
        float w = acc[i][j][r];
        s += w; q += w*w;
        ins3r(w, c0 + wy*64 + i*16 + quad*4 + r, v0,v1,v2,i0,i1,i2);
      }
    #pragma unroll
    for (int msk = 16; msk < 64; msk <<= 1) {     // reduce over quad (same col)
      float ov0=__shfl_xor(v0,msk), ov1=__shfl_xor(v1,msk), ov2=__shfl_xor(v2,msk);
      int   oi0=__shfl_xor(i0,msk), oi1=__shfl_xor(i1,msk), oi2=__shfl_xor(i2,msk);
      float os =__shfl_xor(s,msk),  oq =__shfl_xor(q,msk);
      s += os; q += oq;
      ins3r(ov0,oi0,v0,v1,v2,i0,i1,i2);
      ins3r(ov1,oi1,v0,v1,v2,i0,i1,i2);
      ins3r(ov2,oi2,v0,v1,v2,i0,i1,i2);
    }
    if (quad == 0) {
      float* p = cbuf + (size_t)(j*64 + wave*16 + l15) * 12;  // 12-float recs: 2-way max
      float4 lo = {v0, v1, v2, __int_as_float(i0)};
      float4 hi = {__int_as_float(i1), __int_as_float(i2), s, q};
      *(float4*)p = lo; *(float4*)(p+4) = hi;
    }
  }
  __syncthreads();
  if (tid < 128) {                                // one worker per (col-in-64, j-quad pair)
    // merge the two waves covering the same columns: waves (wy=0,wy=1) share wx
    int txw = tid & 15, jj = (tid >> 4) & 3, wxx = tid >> 6;
    float v0=-3e38f, v1=-3e38f, v2=-3e38f; int i0=-1, i1=-1, i2=-1;
    float s = 0.f, q = 0.f;
    #pragma unroll
    for (int wyy = 0; wyy < 2; wyy++) {
      float* p = cbuf + (size_t)(jj*64 + (wyy*2 + wxx)*16 + txw) * 12;
      float4 lo = *(float4*)p, hi = *(float4*)(p+4);
      ins3r(lo.x, __float_as_int(lo.w), v0,v1,v2,i0,i1,i2);
      ins3r(lo.y, __float_as_int(hi.x), v0,v1,v2,i0,i1,i2);
      ins3r(lo.z, __float_as_int(hi.y), v0,v1,v2,i0,i1,i2);
      s += hi.z; q += hi.w;
    }
    int col = m0 + wxx*64 + jj*16 + txw;
    float* p = colPart + ((size_t)(b*NB2 + cb*2 + 0)*LDIM + col) * 8;
    // NOTE: col slice index must identify the 64-row slice (cb*2 + wy-merged covers 128 rows)
    // we store merged-over-128-rows into slice cb*2; slice cb*2+1 is written as empty-neutral
    float4 lo = {v0, v1, v2, __int_as_float(i0)};
    float4 hi = {__int_as_float(i1), __int_as_float(i2), s, q};
    *(float4*)p = lo; *(float4*)(p+4) = hi;
  }
  if (tid < 128) {                                // neutral filler for the unused slice slot
    int txw = tid & 15, jj = (tid >> 4) & 3, wxx = tid >> 6;
    int col = m0 + wxx*64 + jj*16 + txw;
    float* p = colPart + ((size_t)(b*NB2 + cb*2 + 1)*LDIM + col) * 8;
    float4 lo = {-3e38f, -3e38f, -3e38f, __int_as_float(-1)};
    float4 hi = {__int_as_float(-1), __int_as_float(-1), 0.f, 0.f};
    *(float4*)p = lo; *(float4*)(p+4) = hi;
  }
}

// Merge NB2 slice-partials per line -> normalized top-3 weights, indices, std.
__global__ __launch_bounds__(256) void reduce_stats(const float* __restrict__ part,
    float* __restrict__ w3, int* __restrict__ i3, float* __restrict__ sd) {
  int gid = blockIdx.x * 256 + threadIdx.x;       // over nb*LDIM lines
  int b = gid >> 11, r = gid & 2047;
  float v0=-3e38f, v1=-3e38f, v2=-3e38f; int i0=-1, i1=-1, i2=-1;
  float s = 0.f, q = 0.f;
  for (int blk = 0; blk < NB2; blk++) {
    const float* p = part + ((size_t)(b*NB2 + blk)*LDIM + r) * 8;
    float4 lo = *(const float4*)p, hi = *(const float4*)(p+4);
    ins3r(lo.x, __float_as_int(lo.w), v0,v1,v2,i0,i1,i2);
    ins3r(lo.y, __float_as_int(hi.x), v0,v1,v2,i0,i1,i2);
    ins3r(lo.z, __float_as_int(hi.y), v0,v1,v2,i0,i1,i2);
    s += hi.z; q += hi.w;
  }
  float inv = 1.f / (v0 + v1 + v2);
  w3[(size_t)gid*3+0] = v0*inv; w3[(size_t)gid*3+1] = v1*inv; w3[(size_t)gid*3+2] = v2*inv;
  i3[(size_t)gid*3+0] = i0; i3[(size_t)gid*3+1] = i1; i3[(size_t)gid*3+2] = i2;
  float mean = s * (1.f/LDIM);
  float var  = q * (1.f/LDIM) - mean*mean;
  sd[gid] = sqrtf(fmaxf(var, 0.f));
}

// att_merge_c[m][d] += wk_c[c][m] * ctx[c][d]  -- 3 targets per row c (scatter).
__global__ __launch_bounds__(128) void scatter_att(const float* __restrict__ ctx,
    const float* __restrict__ rw, const int* __restrict__ ri,
    float* __restrict__ attC) {
  const int b = blockIdx.y, c = blockIdx.x, d = threadIdx.x;
  const size_t base = (size_t)b*LDIM + c;
  const float x = ctx[base*DDIM + d];
  #pragma unroll
  for (int t = 0; t < 3; t++) {
    float w = rw[base*3 + t];
    int m = ri[base*3 + t];
    atomicAdd(&attC[((size_t)b*LDIM + m)*DDIM + d], w*x);
  }
}

// outputs_c = |ctx - gather(col top-3 of main)| * row_std ; outputs_m = |main - attC| * col_std
__global__ __launch_bounds__(128) void make_outputs(const float* __restrict__ ctx,
    const float* __restrict__ mn, const float* __restrict__ attC,
    const float* __restrict__ rs, const float* __restrict__ cw,
    const int* __restrict__ ci, const float* __restrict__ cs,
    float* __restrict__ outC, float* __restrict__ outM) {
  const int b = blockIdx.y, i = blockIdx.x, d = threadIdx.x;
  const size_t base = (size_t)b*LDIM + i;
  float am = 0.f;
  #pragma unroll
  for (int t = 0; t < 3; t++)
    am += cw[base*3+t] * mn[((size_t)b*LDIM + ci[base*3+t])*DDIM + d];
  outC[base*DDIM + d] = fabsf(ctx[base*DDIM + d] - am) * rs[base];
  outM[base*DDIM + d] = fabsf(mn[base*DDIM + d] - attC[base*DDIM + d]) * cs[base];
}

// conv1d(KS=3, valid) + bias + relu + maxpool. z=0: outC->pool_c, z=1: outM->pool_m.
__global__ __launch_bounds__(128) void conv_pool(const float* __restrict__ XC,
    const float* __restrict__ XM, const float* __restrict__ wv,
    const float* __restrict__ bias, float* __restrict__ out) {
  const int b = blockIdx.y, z = blockIdx.z;
  const int t0 = blockIdx.x * TCONV;
  const float* X = (z == 0 ? XC : XM) + (size_t)b*LDIM*DDIM;
  __shared__ float Xs[TCONV+2][DDIM];
  const int tid = threadIdx.x;
  for (int e = tid; e < (TCONV+2)*DDIM; e += 128) {
    int tt = e >> 7, d = e & 127;
    int t = t0 + tt;
    Xs[tt][d] = (t < LDIM) ? X[(size_t)t*DDIM + d] : 0.f;
  }
  __syncthreads();
  const int f = tid;
  if (f < FDIM) {
    float y[TCONV];
    #pragma unroll
    for (int t = 0; t < TCONV; t++) y[t] = 0.f;
    for (int dq = 0; dq < DDIM/4; dq++) {
      float4 xq[TCONV+2];
      #pragma unroll
      for (int i = 0; i < TCONV+2; i++) xq[i] = *(const float4*)&Xs[i][dq*4];
      #pragma unroll
      for (int ks = 0; ks < 3; ks++) {
        float w0 = wv[(ks*DDIM + dq*4+0)*FDIM + f];
        float w1 = wv[(ks*DDIM + dq*4+1)*FDIM + f];
        float w2 = wv[(ks*DDIM + dq*4+2)*FDIM + f];
        float w3 = wv[(ks*DDIM + dq*4+3)*FDIM + f];
        #pragma unroll
        for (int t = 0; t < TCONV; t++)
          y[t] += xq[t+ks].x*w0 + xq[t+ks].y*w1 + xq[t+ks].z*w2 + xq[t+ks].w*w3;
      }
    }
    float bv = bias[f];
    float mx = 0.f;
    #pragma unroll
    for (int t = 0; t < TCONV; t++) {
      if (t0 + t < LDIM - 2) mx = fmaxf(mx, fmaxf(y[t] + bv, 0.f));
    }
    atomicMax((unsigned int*)&out[(size_t)b*(2*FDIM) + z*FDIM + f], __float_as_uint(mx));
  }
}

extern "C" void kernel_launch(void* const* d_in, const int* in_sizes, int n_in,
                              void* d_out, int out_size, void* d_ws, size_t ws_size,
                              hipStream_t stream) {
  const float* ctx   = (const float*)d_in[0];
  const float* mn    = (const float*)d_in[1];
  const float* wconv = (const float*)d_in[2];
  const float* bias  = (const float*)d_in[3];
  float* out = (float*)d_out;

  hipMemsetAsync(d_out, 0, sizeof(float)*(size_t)out_size, stream);

  const size_t PB_SPLIT = (size_t)LDIM*KSPLIT/2;              // in float units
  const size_t PB_PART  = (size_t)NB2*LDIM*8;
  const size_t perBatchFloats = 2*PB_SPLIT + 2*PB_PART + 14*(size_t)LDIM + 3*(size_t)LDIM*DDIM;
  const size_t perBatchBytes = perBatchFloats * sizeof(float);
  int nbMax = (int)(ws_size / perBatchBytes);
  if (nbMax < 1) nbMax = 1;
  if (nbMax > BDIM) nbMax = BDIM;

  for (int b0 = 0; b0 < BDIM; b0 += nbMax) {
    const int nb = (BDIM - b0 < nbMax) ? (BDIM - b0) : nbMax;
    unsigned short* A3u = (unsigned short*)d_ws;
    unsigned short* B3u = A3u + (size_t)nb*LDIM*KSPLIT;
    float* rowPart = (float*)d_ws + 2*(size_t)nb*PB_SPLIT;
    float* colPart = rowPart + (size_t)nb*PB_PART;
    float* rowW = colPart + (size_t)nb*PB_PART;
    int*   rowI = (int*)(rowW + (size_t)nb*LDIM*3);
    float* rowS = (float*)(rowI + (size_t)nb*LDIM*3);
    float* colW = rowS + (size_t)nb*LDIM;
    int*   colI = (int*)(colW + (size_t)nb*LDIM*3);
    float* colS = (float*)(colI + (size_t)nb*LDIM*3);
    float* attC = colS + (size_t)nb*LDIM;
    float* outC = attC + (size_t)nb*LDIM*DDIM;
    float* outM = outC + (size_t)nb*LDIM*DDIM;
    const float* ctxb = ctx + (size_t)b0*LDIM*DDIM;
    const float* mnb  = mn  + (size_t)b0*LDIM*DDIM;

    split_bf16<<<dim3(nb*256, 2), 256, 0, stream>>>(ctxb, mnb, A3u, B3u);
    gemm_mfma<<<dim3(NB2/2, NB2/2, nb), 256, 0, stream>>>(A3u, B3u, rowPart, colPart);
    reduce_stats<<<dim3(nb*8), 256, 0, stream>>>(rowPart, rowW, rowI, rowS);
    reduce_stats<<<dim3(nb*8), 256, 0, stream>>>(colPart, colW, colI, colS);
    hipMemsetAsync(attC, 0, (size_t)nb*LDIM*DDIM*sizeof(float), stream);
    scatter_att<<<dim3(LDIM, nb), 128, 0, stream>>>(ctxb, rowW, rowI, attC);
    make_outputs<<<dim3(LDIM, nb), 128, 0, stream>>>(ctxb, mnb, attC, rowS, colW, colI, colS, outC, outM);
    conv_pool<<<dim3((LDIM - 2 + TCONV - 1)/TCONV, nb, 2), 128, 0, stream>>>(
        outC, outM, wconv, bias, out + (size_t)b0*2*FDIM);
  }
}